// Round 2
// baseline (3722.862 us; speedup 1.0000x reference)
//
#include <hip/hip_runtime.h>
#include <hip/hip_bf16.h>
#include <math.h>

// Problem dims
#define DI 69      // input feature dim
#define EE 132     // time2vec dim
#define RR 1024    // rnn size
#define BB 2048    // batch
#define TT 25      // target seq len
#define SE 49      // source seq len - 1

typedef _Float16 f16;
typedef _Float16 v8h __attribute__((ext_vector_type(8)));
typedef float f32x4 __attribute__((ext_vector_type(4)));

__device__ __forceinline__ float sigm(float x) { return 1.0f / (1.0f + __expf(-x)); }
__device__ __forceinline__ float tanhf_fast(float x) {
  float e = __expf(2.0f * x);          // inf-safe: x>>0 -> 1, x<<0 -> -1
  return 1.0f - 2.0f / (e + 1.0f);
}

// ---------------- prep kernels ----------------

__global__ void prep_misc_kernel(float* __restrict__ c, f16* __restrict__ h0,
                                 const float* __restrict__ bih_e, const float* __restrict__ bhh_e,
                                 const float* __restrict__ bih_d, const float* __restrict__ bhh_d,
                                 float* __restrict__ bias_e, float* __restrict__ bias_d,
                                 const float* __restrict__ fc1_w, f16* __restrict__ fc1h)
{
  int i = blockIdx.x * 256 + threadIdx.x;   // grid covers BB*RR = 2M
  if (i < BB * RR) { c[i] = 0.0f; h0[i] = (f16)0.0f; }
  if (i < 4096) { bias_e[i] = bih_e[i] + bhh_e[i]; bias_d[i] = bih_d[i] + bhh_d[i]; }
  if (i < 80 * RR) {
    int dr = i >> 10, k = i & 1023;
    fc1h[i] = (f16)((dr < DI) ? fc1_w[dr * RR + k] : 0.0f);
  }
}

// Pack per-gate weights: Wq[j][k], j = gate*1024+unit (same row order as torch),
// k<1024 = Whh row, k>=1024 = Wih row (feature part), zero-padded to KT.
__global__ void prep_wq_kernel(const float* __restrict__ Whh, const float* __restrict__ Wih,
                               f16* __restrict__ Wq, int KT, int DIN)
{
  int j = blockIdx.x;   // 0..4095
  for (int k = threadIdx.x; k < KT; k += blockDim.x) {
    float v;
    if (k < RR) v = Whh[(size_t)j * RR + k];
    else { int kk = k - RR; v = (kk < DIN) ? Wih[(size_t)j * DIN + kk] : 0.0f; }
    Wq[(size_t)j * KT + k] = (f16)v;
  }
}

// feat_enc[t][b][0:69]=x, [69:201]=sin(x@t2v_w^T+t2v_b), [201:256]=0   (fp16)
__global__ void feat_enc_kernel(const float* __restrict__ enc_in,
                                const float* __restrict__ t2v_w, const float* __restrict__ t2v_b,
                                f16* __restrict__ feat)
{
  int blk = blockIdx.x;          // t*BB + b
  int t = blk >> 11, b = blk & (BB - 1);
  __shared__ float x[DI];
  int tid = threadIdx.x;
  if (tid < DI) x[tid] = enc_in[(size_t)b * SE * DI + t * DI + tid];
  __syncthreads();
  f16* dst = feat + (size_t)blk * 256;
  if (tid < DI) dst[tid] = (f16)x[tid];
  else if (tid < DI + EE) {
    int r = tid - DI;
    float s = t2v_b[r];
    const float* w = t2v_w + r * DI;
    for (int d = 0; d < DI; ++d) s += x[d] * w[d];
    dst[tid] = (f16)sinf(s);
  } else dst[tid] = (f16)0.0f;
}

// feat_dec[t][b][0:69] = decoder_inputs[b][t][:], [69:128]=0   (fp16)
__global__ void feat_dec_kernel(const float* __restrict__ dec_in, f16* __restrict__ feat)
{
  int idx = blockIdx.x * 256 + threadIdx.x;
  if (idx >= TT * BB * 128) return;
  int k = idx & 127;
  int r = idx >> 7;              // t*BB + b
  int t = r >> 11, b = r & (BB - 1);
  feat[idx] = (f16)((k < DI) ? dec_in[(size_t)b * TT * DI + t * DI + k] : 0.0f);
}

// ---------------- fused LSTM step: gates GEMM + cell update ----------------
// Block: 128 rows x 32 units (x4 gates). 256 threads = 4 waves (2x2).
// A = [h | feat] fp16 (two pointers), B = Wq fp16 [4][1024][KT] N-major.
// Epilogue: all 4 gates for (row,unit) are in the same lane -> no cross-lane.
template<int KT, int FPAD, bool WF32>
__global__ __launch_bounds__(256, 2)
void lstm_step_kernel(const f16* __restrict__ hin, const f16* __restrict__ feat,
                      const f16* __restrict__ Wq, const float* __restrict__ bias,
                      float* __restrict__ c, f16* __restrict__ hout,
                      float* __restrict__ hf32)
{
  __shared__ __align__(16) f16 lA[128 * 72];   // [128 rows][64 k] pad->72
  __shared__ __align__(16) f16 lB[128 * 72];   // [4 gates][32 units][64 k] pad->72
  const int tid = threadIdx.x;
  const int m0 = blockIdx.y * 128;
  const int u0 = blockIdx.x * 32;
  const int lane = tid & 63, wid = tid >> 6;
  const int wm = wid >> 1, wn = wid & 1;
  const int lrow = lane & 15, lk = (lane >> 4) * 8;

  f32x4 acc[4][4];   // [m-frag][gate]
  #pragma unroll
  for (int a = 0; a < 4; ++a)
    #pragma unroll
    for (int g = 0; g < 4; ++g) acc[a][g] = (f32x4){0.f, 0.f, 0.f, 0.f};

  constexpr int NIT = KT / 64;
  for (int kt = 0; kt < NIT; ++kt) {
    const int k0 = kt * 64;
    #pragma unroll
    for (int i = 0; i < 4; ++i) {
      int chunk = tid + 256 * i;          // 1024 chunks of 16B
      int row = chunk >> 3;
      int koff = (chunk & 7) * 8;
      int kg = k0 + koff;
      const f16* src = (kg < RR) ? (hin + (size_t)(m0 + row) * RR + kg)
                                 : (feat + (size_t)(m0 + row) * FPAD + (kg - RR));
      *(uint4*)(&lA[row * 72 + koff]) = *(const uint4*)src;
      int wrow = ((row >> 5) << 10) + u0 + (row & 31);   // gate*1024 + unit
      *(uint4*)(&lB[row * 72 + koff]) = *(const uint4*)(Wq + (size_t)wrow * KT + k0 + koff);
    }
    __syncthreads();
    const f16* Ab = &lA[(wm * 64 + lrow) * 72 + lk];
    const f16* Bb = &lB[(wn * 16 + lrow) * 72 + lk];
    #pragma unroll
    for (int kk = 0; kk < 2; ++kk) {
      v8h av[4], bv[4];
      #pragma unroll
      for (int mf = 0; mf < 4; ++mf) av[mf] = *(const v8h*)(Ab + mf * 16 * 72 + kk * 32);
      #pragma unroll
      for (int g = 0; g < 4; ++g)   bv[g]  = *(const v8h*)(Bb + g * 32 * 72 + kk * 32);
      #pragma unroll
      for (int mf = 0; mf < 4; ++mf)
        #pragma unroll
        for (int g = 0; g < 4; ++g)
          acc[mf][g] = __builtin_amdgcn_mfma_f32_16x16x32_f16(av[mf], bv[g], acc[mf][g], 0, 0, 0);
    }
    __syncthreads();
  }

  // epilogue: gate order i,f,g,o ; C layout col=lane&15, row=(lane>>4)*4+reg
  const int u = u0 + wn * 16 + lrow;
  const float bi = bias[u], bf = bias[1024 + u], bg = bias[2048 + u], bo = bias[3072 + u];
  #pragma unroll
  for (int mf = 0; mf < 4; ++mf) {
    int rbase = m0 + wm * 64 + mf * 16 + (lane >> 4) * 4;
    #pragma unroll
    for (int q = 0; q < 4; ++q) {
      int r = rbase + q;
      size_t idx = (size_t)r * RR + u;
      float iv = acc[mf][0][q] + bi;
      float fv = acc[mf][1][q] + bf;
      float gv = acc[mf][2][q] + bg;
      float ov = acc[mf][3][q] + bo;
      float cn = sigm(fv) * c[idx] + sigm(iv) * tanhf_fast(gv);
      float hn = sigm(ov) * tanhf_fast(cn);
      c[idx] = cn;
      hout[idx] = (f16)hn;
      if (WF32) hf32[idx] = hn;
    }
  }
}

// ---------------- mu/sigma normalize + noise ----------------
__global__ void musigma_kernel(const float* __restrict__ hf, float* __restrict__ c,
                               const float* __restrict__ noise,
                               const float* __restrict__ mu_w, const float* __restrict__ mu_b,
                               const float* __restrict__ sig_w, const float* __restrict__ sig_b,
                               f16* __restrict__ hout)
{
  int b = blockIdx.x, tid = threadIdx.x;
  __shared__ float red[8];
  __shared__ float musig[2];
  float sh = 0.f, sc = 0.f;
  for (int k = tid; k < RR; k += 256) {
    size_t idx = (size_t)b * RR + k;
    sh += hf[idx] * mu_w[k];
    sc += c[idx] * sig_w[k];
  }
  for (int off = 32; off > 0; off >>= 1) { sh += __shfl_down(sh, off); sc += __shfl_down(sc, off); }
  int wid = tid >> 6;
  if ((tid & 63) == 0) { red[wid] = sh; red[4 + wid] = sc; }
  __syncthreads();
  if (tid == 0) {
    musig[0] = red[0] + red[1] + red[2] + red[3] + mu_b[0];
    musig[1] = red[4] + red[5] + red[6] + red[7] + sig_b[0];
  }
  __syncthreads();
  float mu = musig[0], sg = musig[1];
  for (int k = tid; k < RR; k += 256) {
    size_t idx = (size_t)b * RR + k;
    float n10 = 10.0f * noise[idx];
    float hh = (hf[idx] - mu) / sg + n10;
    float cc = (c[idx] - mu) / sg + n10;
    hout[idx] = (f16)hh;
    c[idx] = cc;
  }
}

// ---------------- final residual projection: out = x + Hdec @ fc1^T + b ----------------
__global__ __launch_bounds__(256, 2)
void final_fc_kernel(const f16* __restrict__ Hd, const f16* __restrict__ fw,
                     const float* __restrict__ fb, const float* __restrict__ dec_in,
                     float* __restrict__ out)
{
  __shared__ __align__(16) f16 lA[128 * 72];
  __shared__ __align__(16) f16 lB[80 * 72];
  const int tid = threadIdx.x;
  const int m0 = blockIdx.x * 128;        // rows = t*BB + b, 51200 total
  const int lane = tid & 63, wid = tid >> 6;
  const int lrow = lane & 15, lk = (lane >> 4) * 8;
  f32x4 acc[2][5];
  #pragma unroll
  for (int a = 0; a < 2; ++a)
    #pragma unroll
    for (int n = 0; n < 5; ++n) acc[a][n] = (f32x4){0.f, 0.f, 0.f, 0.f};

  for (int kt = 0; kt < 16; ++kt) {
    int k0 = kt * 64;
    #pragma unroll
    for (int i = 0; i < 4; ++i) {
      int chunk = tid + 256 * i;
      int row = chunk >> 3, koff = (chunk & 7) * 8;
      *(uint4*)(&lA[row * 72 + koff]) = *(const uint4*)(Hd + (size_t)(m0 + row) * RR + k0 + koff);
    }
    #pragma unroll
    for (int i = 0; i < 3; ++i) {
      int chunk = tid + 256 * i;
      if (chunk < 640) {
        int row = chunk >> 3, koff = (chunk & 7) * 8;
        *(uint4*)(&lB[row * 72 + koff]) = *(const uint4*)(fw + (size_t)row * RR + k0 + koff);
      }
    }
    __syncthreads();
    const f16* Ab = &lA[(wid * 32 + lrow) * 72 + lk];
    const f16* Bb = &lB[lrow * 72 + lk];
    #pragma unroll
    for (int kk = 0; kk < 2; ++kk) {
      v8h av[2], bv[5];
      #pragma unroll
      for (int mf = 0; mf < 2; ++mf) av[mf] = *(const v8h*)(Ab + mf * 16 * 72 + kk * 32);
      #pragma unroll
      for (int nf = 0; nf < 5; ++nf) bv[nf] = *(const v8h*)(Bb + nf * 16 * 72 + kk * 32);
      #pragma unroll
      for (int mf = 0; mf < 2; ++mf)
        #pragma unroll
        for (int nf = 0; nf < 5; ++nf)
          acc[mf][nf] = __builtin_amdgcn_mfma_f32_16x16x32_f16(av[mf], bv[nf], acc[mf][nf], 0, 0, 0);
    }
    __syncthreads();
  }
  #pragma unroll
  for (int mf = 0; mf < 2; ++mf) {
    int rbase = m0 + wid * 32 + mf * 16 + (lane >> 4) * 4;
    #pragma unroll
    for (int nf = 0; nf < 5; ++nf) {
      int col = nf * 16 + lrow;
      if (col < DI) {
        #pragma unroll
        for (int q = 0; q < 4; ++q) {
          int m = rbase + q;
          int t = m >> 11, b = m & (BB - 1);
          size_t oi = (size_t)b * TT * DI + t * DI + col;
          out[oi] = acc[mf][nf][q] + fb[col] + dec_in[oi];
        }
      }
    }
  }
}

// ---------------- launch ----------------
extern "C" void kernel_launch(void* const* d_in, const int* in_sizes, int n_in,
                              void* d_out, int out_size, void* d_ws, size_t ws_size,
                              hipStream_t stream)
{
  const float* enc_in = (const float*)d_in[0];
  const float* dec_in = (const float*)d_in[1];
  const float* noise  = (const float*)d_in[2];
  const float* Wih_e  = (const float*)d_in[3];
  const float* Whh_e  = (const float*)d_in[4];
  const float* bih_e  = (const float*)d_in[5];
  const float* bhh_e  = (const float*)d_in[6];
  const float* Wih_d  = (const float*)d_in[7];
  const float* Whh_d  = (const float*)d_in[8];
  const float* bih_d  = (const float*)d_in[9];
  const float* bhh_d  = (const float*)d_in[10];
  const float* fc1_w  = (const float*)d_in[11];
  const float* fc1_b  = (const float*)d_in[12];
  const float* mu_w   = (const float*)d_in[13];
  const float* mu_b   = (const float*)d_in[14];
  const float* sig_w  = (const float*)d_in[15];
  const float* sig_b  = (const float*)d_in[16];
  const float* t2v_w  = (const float*)d_in[17];
  const float* t2v_b  = (const float*)d_in[18];
  float* outp = (float*)d_out;

  char* ws = (char*)d_ws;
  size_t off = 0;
  auto alloc = [&](size_t bytes) -> char* {
    char* p = ws + off; off += (bytes + 255) & ~(size_t)255; return p;
  };
  f16*   wq_e   = (f16*)alloc((size_t)4096 * 1280 * 2);
  f16*   wq_d   = (f16*)alloc((size_t)4096 * 1152 * 2);
  f16*   fc1h   = (f16*)alloc((size_t)80 * RR * 2);
  float* bias_e = (float*)alloc(4096 * 4);
  float* bias_d = (float*)alloc(4096 * 4);
  f16*   feat_e = (f16*)alloc((size_t)SE * BB * 256 * 2);
  f16*   feat_d = (f16*)alloc((size_t)TT * BB * 128 * 2);
  f16*   h_ping = (f16*)alloc((size_t)BB * RR * 2);
  f16*   h_pong = (f16*)alloc((size_t)BB * RR * 2);
  float* cbuf   = (float*)alloc((size_t)BB * RR * 4);
  float* hf32   = (float*)alloc((size_t)BB * RR * 4);
  f16*   Hd     = (f16*)alloc((size_t)TT * BB * RR * 2);
  if (off > ws_size) return;   // workspace too small -> clean failure

  // prep
  prep_misc_kernel<<<(BB * RR + 255) / 256, 256, 0, stream>>>(
      cbuf, h_ping, bih_e, bhh_e, bih_d, bhh_d, bias_e, bias_d, fc1_w, fc1h);
  prep_wq_kernel<<<4096, 256, 0, stream>>>(Whh_e, Wih_e, wq_e, 1280, DI + EE);
  prep_wq_kernel<<<4096, 256, 0, stream>>>(Whh_d, Wih_d, wq_d, 1152, DI);
  feat_enc_kernel<<<SE * BB, 256, 0, stream>>>(enc_in, t2v_w, t2v_b, feat_e);
  feat_dec_kernel<<<(TT * BB * 128 + 255) / 256, 256, 0, stream>>>(dec_in, feat_d);

  dim3 sgrid(32, 16, 1);   // 1024/32 units x 2048/128 rows

  // encoder: 49 steps, h ping-pong, c in-place
  f16* hcur = h_ping; f16* hnxt = h_pong;
  for (int t = 0; t < SE; ++t) {
    const f16* ft = feat_e + (size_t)t * BB * 256;
    if (t == SE - 1)
      lstm_step_kernel<1280, 256, true><<<sgrid, 256, 0, stream>>>(
          hcur, ft, wq_e, bias_e, cbuf, hnxt, hf32);
    else
      lstm_step_kernel<1280, 256, false><<<sgrid, 256, 0, stream>>>(
          hcur, ft, wq_e, bias_e, cbuf, hnxt, nullptr);
    f16* tmp = hcur; hcur = hnxt; hnxt = tmp;
  }

  // normalize + noise (reads fp32 h, writes fp16 h into h_ping, c in-place)
  musigma_kernel<<<BB, 256, 0, stream>>>(hf32, cbuf, noise, mu_w, mu_b, sig_w, sig_b, h_ping);

  // decoder: 25 steps, h chained through Hd slices
  const f16* din = h_ping;
  for (int t = 0; t < TT; ++t) {
    f16* hout = Hd + (size_t)t * BB * RR;
    lstm_step_kernel<1152, 128, false><<<sgrid, 256, 0, stream>>>(
        din, feat_d + (size_t)t * BB * 128, wq_d, bias_d, cbuf, hout, nullptr);
    din = hout;
  }

  // out = dec_in + Hdec @ fc1^T + fc1_b
  final_fc_kernel<<<(TT * BB) / 128, 256, 0, stream>>>(Hd, fc1h, fc1_b, dec_in, outp);
}

// Round 3
// 2407.389 us; speedup vs baseline: 1.5464x; 1.5464x over previous
//
#include <hip/hip_runtime.h>
#include <hip/hip_bf16.h>
#include <math.h>

// Problem dims
#define DI 69      // input feature dim
#define EE 132     // time2vec dim
#define RR 1024    // rnn size
#define BB 2048    // batch
#define TT 25      // target seq len
#define SE 49      // source seq len - 1

typedef _Float16 f16;
typedef _Float16 v8h __attribute__((ext_vector_type(8)));
typedef float f32x4 __attribute__((ext_vector_type(4)));

__device__ __forceinline__ float sigm(float x) { return 1.0f / (1.0f + __expf(-x)); }
__device__ __forceinline__ float tanhf_fast(float x) {
  float e = __expf(2.0f * x);          // inf-safe: x>>0 -> 1, x<<0 -> -1
  return 1.0f - 2.0f / (e + 1.0f);
}

// async global->LDS, 16B per lane. LDS dest must be wave-uniform base; lane l
// writes bytes [base + l*16, base + l*16 + 16) from its own global address.
typedef const __attribute__((address_space(1))) char* gas1p;
typedef __attribute__((address_space(3))) char* las3p;
__device__ __forceinline__ void gld16(const void* g, void* l) {
  __builtin_amdgcn_global_load_lds((gas1p)g, (las3p)l, 16, 0, 0);
}

// Global h/feat/W layouts are PRE-SWIZZLED: element (row, k) lives at
// k' = k ^ ((row&7)<<3)  (XOR on half-index bits 3..5, i.e. 16B slot bits
// within each 64-half (128B) K-tile). Staging to LDS is then fully linear
// (global_load_lds), and ds_reads apply the same XOR -> conflict-free.

// ---------------- prep kernels ----------------

__global__ void prep_misc_kernel(float* __restrict__ c, f16* __restrict__ h0,
                                 const float* __restrict__ bih_e, const float* __restrict__ bhh_e,
                                 const float* __restrict__ bih_d, const float* __restrict__ bhh_d,
                                 float* __restrict__ bias_e, float* __restrict__ bias_d,
                                 const float* __restrict__ fc1_w, f16* __restrict__ fc1h)
{
  int i = blockIdx.x * 256 + threadIdx.x;   // grid covers BB*RR = 2M
  if (i < BB * RR) { c[i] = 0.0f; h0[i] = (f16)0.0f; }
  if (i < 4096) { bias_e[i] = bih_e[i] + bhh_e[i]; bias_d[i] = bih_d[i] + bhh_d[i]; }
  if (i < 128 * RR) {   // fc1h padded to 128 rows, swizzled
    int dr = i >> 10, k = i & 1023;
    int kd = k ^ ((dr & 7) << 3);
    fc1h[(dr << 10) | kd] = (f16)((dr < DI) ? fc1_w[dr * RR + k] : 0.0f);
  }
}

// Pack per-gate weights: Wq[j][k'], j = gate*1024+unit (torch row order),
// k<1024 = Whh row, k>=1024 = Wih row (feature part), zero-padded to KT.
__global__ void prep_wq_kernel(const float* __restrict__ Whh, const float* __restrict__ Wih,
                               f16* __restrict__ Wq, int KT, int DIN)
{
  int j = blockIdx.x;   // 0..4095
  int xo = (j & 7) << 3;
  for (int k = threadIdx.x; k < KT; k += blockDim.x) {
    float v;
    if (k < RR) v = Whh[(size_t)j * RR + k];
    else { int kk = k - RR; v = (kk < DIN) ? Wih[(size_t)j * DIN + kk] : 0.0f; }
    Wq[(size_t)j * KT + (k ^ xo)] = (f16)v;
  }
}

// feat_enc[t][b][0:69]=x, [69:201]=sin(x@t2v_w^T+t2v_b), [201:256]=0 (f16, swizzled)
// Register-tiled 4x4 VALU GEMM: block = one t, 32 batch rows, full 132 e.
__global__ __launch_bounds__(256)
void feat_enc_kernel(const float* __restrict__ enc_in,
                     const float* __restrict__ t2v_w, const float* __restrict__ t2v_b,
                     f16* __restrict__ feat)
{
  __shared__ float wl[132 * 100];   // row stride 100 floats (400B) -> bank spread
  __shared__ float xl[32 * 92];     // row stride 92 floats (368B)
  __shared__ float bl[132];
  const int tid = threadIdx.x;
  const int t = blockIdx.x >> 6;          // 64 blocks per t
  const int b0 = (blockIdx.x & 63) * 32;

  for (int i = tid; i < 132 * 18; i += 256) {
    int e = i / 18, s = i - e * 18, k = s * 4;
    const float* src = t2v_w + e * DI + k;
    float4 v;
    v.x = src[0];
    v.y = (k + 1 < DI) ? src[1] : 0.f;
    v.z = (k + 2 < DI) ? src[2] : 0.f;
    v.w = (k + 3 < DI) ? src[3] : 0.f;
    *(float4*)(wl + e * 100 + k) = v;
  }
  for (int i = tid; i < 32 * 18; i += 256) {
    int r = i / 18, s = i - r * 18, k = s * 4;
    const float* src = enc_in + ((size_t)(b0 + r) * SE + t) * DI + k;
    float4 v;
    v.x = src[0];
    v.y = (k + 1 < DI) ? src[1] : 0.f;
    v.z = (k + 2 < DI) ? src[2] : 0.f;
    v.w = (k + 3 < DI) ? src[3] : 0.f;
    *(float4*)(xl + r * 92 + k) = v;
  }
  if (tid < 132) bl[tid] = t2v_b[tid];
  __syncthreads();

  const int gr = tid >> 5, ge = tid & 31;       // 8 row-groups x 32 e-groups
  float acc[4][4] = {};
  const float* xr = xl + (gr * 4) * 92;
  for (int k4 = 0; k4 < 18; ++k4) {
    float4 xv[4], wv[4];
    #pragma unroll
    for (int i = 0; i < 4; ++i) xv[i] = *(const float4*)(xr + i * 92 + k4 * 4);
    #pragma unroll
    for (int j = 0; j < 4; ++j) wv[j] = *(const float4*)(wl + (ge + 32 * j) * 100 + k4 * 4);
    #pragma unroll
    for (int i = 0; i < 4; ++i)
      #pragma unroll
      for (int j = 0; j < 4; ++j)
        acc[i][j] += xv[i].x * wv[j].x + xv[i].y * wv[j].y + xv[i].z * wv[j].z + xv[i].w * wv[j].w;
  }
  #pragma unroll
  for (int i = 0; i < 4; ++i) {
    int b = b0 + gr * 4 + i;
    size_t base = ((size_t)t * BB + b) * 256;
    int xo = (b & 7) << 3;
    #pragma unroll
    for (int j = 0; j < 4; ++j) {
      int e = ge + 32 * j;                       // e in 0..127
      feat[base + ((69 + e) ^ xo)] = (f16)__sinf(acc[i][j] + bl[e]);
    }
  }
  // leftover e = 128..131, 32 rows handled by threads 0..31
  if (tid < 32) {
    int b = b0 + tid;
    float a2[4] = {0.f, 0.f, 0.f, 0.f};
    for (int k4 = 0; k4 < 18; ++k4) {
      float4 xv = *(const float4*)(xl + tid * 92 + k4 * 4);
      #pragma unroll
      for (int j = 0; j < 4; ++j) {
        float4 wv = *(const float4*)(wl + (128 + j) * 100 + k4 * 4);
        a2[j] += xv.x * wv.x + xv.y * wv.y + xv.z * wv.z + xv.w * wv.w;
      }
    }
    size_t base = ((size_t)t * BB + b) * 256;
    int xo = (b & 7) << 3;
    #pragma unroll
    for (int j = 0; j < 4; ++j)
      feat[base + ((197 + j) ^ xo)] = (f16)__sinf(a2[j] + bl[128 + j]);
  }
  // x part + zero tail
  for (int i = tid; i < 32 * 256; i += 256) {
    int r = i >> 8, k = i & 255;
    if (k >= 69 && k < 201) continue;
    float v = (k < DI) ? xl[r * 92 + k] : 0.f;
    int b = b0 + r;
    feat[((size_t)t * BB + b) * 256 + (k ^ ((b & 7) << 3))] = (f16)v;
  }
}

// feat_dec[t][b][0:69] = decoder_inputs[b][t][:], [69:128]=0  (f16, swizzled)
__global__ void feat_dec_kernel(const float* __restrict__ dec_in, f16* __restrict__ feat)
{
  int idx = blockIdx.x * 256 + threadIdx.x;
  if (idx >= TT * BB * 128) return;
  int k = idx & 127;
  int r = idx >> 7;              // t*BB + b
  int t = r >> 11, b = r & (BB - 1);
  float v = (k < DI) ? dec_in[(size_t)b * TT * DI + t * DI + k] : 0.0f;
  feat[((size_t)r << 7) | (k ^ ((b & 7) << 3))] = (f16)v;
}

// ---------------- fused LSTM step: gates GEMM + cell update ----------------
// Block: 128 rows x 32 units (x4 gates out = 128x128). 256 threads = 4 waves.
// Staging: global_load_lds dwordx4, linear LDS; reads XOR-deswizzle.
// Wave w stages A rows w*32..w*32+31 and B gate w; MFMA: wave (wm,wn) owns
// 64 rows x 16 units x 4 gates.
template<int FT, int FPAD, bool WF32>
__global__ __launch_bounds__(256, 2)
void lstm_step_kernel(const f16* __restrict__ hin, const f16* __restrict__ feat,
                      const f16* __restrict__ Wq, const float* __restrict__ bias,
                      float* __restrict__ c, f16* __restrict__ hout,
                      float* __restrict__ hf32)
{
  constexpr int KT = (16 + FT) * 64;
  __shared__ __align__(16) f16 lA[128 * 64];   // 16 KB, linear
  __shared__ __align__(16) f16 lB[128 * 64];   // 16 KB, linear
  const int tid = threadIdx.x;
  const int m0 = blockIdx.y * 128;
  const int u0 = blockIdx.x * 32;
  const int lane = tid & 63, w = tid >> 6;
  const int wm = w >> 1, wn = w & 1;
  const int lrow = lane & 15;
  const int r8 = lane >> 3, s8 = lane & 7;     // staging: row-in-8, 16B slot

  // staging pointers: 4 gld16 per wave per operand per K-tile
  const f16* pA[4]; const f16* pB[4];
  f16* dA[4]; f16* dB[4];
  #pragma unroll
  for (int i = 0; i < 4; ++i) {
    int rA = w * 32 + 8 * i;
    dA[i] = lA + rA * 64;
    dB[i] = lB + rA * 64;
    pA[i] = hin + (size_t)(m0 + rA + r8) * RR + s8 * 8;
    pB[i] = Wq + (size_t)(w * 1024 + u0 + 8 * i + r8) * KT + s8 * 8;
  }

  f32x4 acc[4][4];   // [m-frag][gate]
  #pragma unroll
  for (int a = 0; a < 4; ++a)
    #pragma unroll
    for (int g = 0; g < 4; ++g) acc[a][g] = (f32x4){0.f, 0.f, 0.f, 0.f};

  // deswizzled read base addrs (halves): slot' = slot ^ (row&7), row&7 == lane&7
  const int sw0 = (((lane >> 4)) ^ s8) * 8;
  const int sw1 = (((lane >> 4) | 4) ^ s8) * 8;
  const f16* a0 = lA + (wm * 64 + lrow) * 64 + sw0;
  const f16* a1 = lA + (wm * 64 + lrow) * 64 + sw1;
  const f16* b0 = lB + (wn * 16 + lrow) * 64 + sw0;
  const f16* b1 = lB + (wn * 16 + lrow) * 64 + sw1;

  for (int kt = 0; kt < 16 + FT; ++kt) {
    if (kt == 16) {   // switch A source from h to feat
      #pragma unroll
      for (int i = 0; i < 4; ++i)
        pA[i] = feat + (size_t)(m0 + w * 32 + 8 * i + r8) * FPAD + s8 * 8;
    }
    #pragma unroll
    for (int i = 0; i < 4; ++i) { gld16(pA[i], dA[i]); pA[i] += 64; }
    #pragma unroll
    for (int i = 0; i < 4; ++i) { gld16(pB[i], dB[i]); pB[i] += 64; }
    __syncthreads();   // drains vmcnt (compiler-inserted)

    v8h av0[4], av1[4], bv0[4], bv1[4];
    #pragma unroll
    for (int mf = 0; mf < 4; ++mf) {
      av0[mf] = *(const v8h*)(a0 + mf * 1024);
      av1[mf] = *(const v8h*)(a1 + mf * 1024);
    }
    #pragma unroll
    for (int g = 0; g < 4; ++g) {
      bv0[g] = *(const v8h*)(b0 + g * 2048);
      bv1[g] = *(const v8h*)(b1 + g * 2048);
    }
    #pragma unroll
    for (int mf = 0; mf < 4; ++mf)
      #pragma unroll
      for (int g = 0; g < 4; ++g) {
        acc[mf][g] = __builtin_amdgcn_mfma_f32_16x16x32_f16(av0[mf], bv0[g], acc[mf][g], 0, 0, 0);
        acc[mf][g] = __builtin_amdgcn_mfma_f32_16x16x32_f16(av1[mf], bv1[g], acc[mf][g], 0, 0, 0);
      }
    __syncthreads();
  }

  // epilogue: gate order i,f,g,o ; C layout col=lane&15, row=(lane>>4)*4+reg
  const int u = u0 + wn * 16 + lrow;
  const float bi = bias[u], bf = bias[1024 + u], bg = bias[2048 + u], bo = bias[3072 + u];
  #pragma unroll
  for (int mf = 0; mf < 4; ++mf) {
    int rbase = m0 + wm * 64 + mf * 16 + (lane >> 4) * 4;
    #pragma unroll
    for (int q = 0; q < 4; ++q) {
      int r = rbase + q;
      size_t idxc = (size_t)r * RR + u;
      float iv = acc[mf][0][q] + bi;
      float fv = acc[mf][1][q] + bf;
      float gv = acc[mf][2][q] + bg;
      float ov = acc[mf][3][q] + bo;
      float cn = sigm(fv) * c[idxc] + sigm(iv) * tanhf_fast(gv);
      float hn = sigm(ov) * tanhf_fast(cn);
      c[idxc] = cn;
      hout[(size_t)r * RR + (u ^ ((r & 7) << 3))] = (f16)hn;   // swizzled
      if (WF32) hf32[idxc] = hn;                                // plain
    }
  }
}

// ---------------- mu/sigma normalize + noise ----------------
__global__ void musigma_kernel(const float* __restrict__ hf, float* __restrict__ c,
                               const float* __restrict__ noise,
                               const float* __restrict__ mu_w, const float* __restrict__ mu_b,
                               const float* __restrict__ sig_w, const float* __restrict__ sig_b,
                               f16* __restrict__ hout)
{
  int b = blockIdx.x, tid = threadIdx.x;
  __shared__ float red[8];
  __shared__ float musig[2];
  float sh = 0.f, sc = 0.f;
  for (int k = tid; k < RR; k += 256) {
    size_t idx = (size_t)b * RR + k;
    sh += hf[idx] * mu_w[k];
    sc += c[idx] * sig_w[k];
  }
  for (int off = 32; off > 0; off >>= 1) { sh += __shfl_down(sh, off); sc += __shfl_down(sc, off); }
  int wid = tid >> 6;
  if ((tid & 63) == 0) { red[wid] = sh; red[4 + wid] = sc; }
  __syncthreads();
  if (tid == 0) {
    musig[0] = red[0] + red[1] + red[2] + red[3] + mu_b[0];
    musig[1] = red[4] + red[5] + red[6] + red[7] + sig_b[0];
  }
  __syncthreads();
  float mu = musig[0], sg = musig[1];
  int xo = (b & 7) << 3;
  for (int k = tid; k < RR; k += 256) {
    size_t idx = (size_t)b * RR + k;
    float n10 = 10.0f * noise[idx];
    float hh = (hf[idx] - mu) / sg + n10;
    float cc = (c[idx] - mu) / sg + n10;
    hout[(size_t)b * RR + (k ^ xo)] = (f16)hh;   // swizzled
    c[idx] = cc;                                  // plain
  }
}

// ---------------- final residual projection: out = x + Hdec @ fc1^T + b ----------------
__global__ __launch_bounds__(256, 2)
void final_fc_kernel(const f16* __restrict__ Hd, const f16* __restrict__ fw,
                     const float* __restrict__ fb, const float* __restrict__ dec_in,
                     float* __restrict__ out)
{
  __shared__ __align__(16) f16 lA[128 * 64];
  __shared__ __align__(16) f16 lB[128 * 64];
  const int tid = threadIdx.x;
  const int m0 = blockIdx.x * 128;        // rows = t*BB + b, 51200 total
  const int lane = tid & 63, w = tid >> 6;
  const int lrow = lane & 15;
  const int r8 = lane >> 3, s8 = lane & 7;

  const f16* pA[4]; const f16* pB[4];
  f16* dA[4]; f16* dB[4];
  #pragma unroll
  for (int i = 0; i < 4; ++i) {
    int rA = w * 32 + 8 * i;
    dA[i] = lA + rA * 64;
    dB[i] = lB + rA * 64;
    pA[i] = Hd + (size_t)(m0 + rA + r8) * RR + s8 * 8;
    pB[i] = fw + (size_t)(rA + r8) * RR + s8 * 8;   // fc1h padded to 128 rows
  }

  f32x4 acc[2][5];
  #pragma unroll
  for (int a = 0; a < 2; ++a)
    #pragma unroll
    for (int n = 0; n < 5; ++n) acc[a][n] = (f32x4){0.f, 0.f, 0.f, 0.f};

  const int sw0 = (((lane >> 4)) ^ s8) * 8;
  const int sw1 = (((lane >> 4) | 4) ^ s8) * 8;
  const f16* a0 = lA + (w * 32 + lrow) * 64 + sw0;
  const f16* a1 = lA + (w * 32 + lrow) * 64 + sw1;
  const f16* b0 = lB + lrow * 64 + sw0;
  const f16* b1 = lB + lrow * 64 + sw1;

  for (int kt = 0; kt < 16; ++kt) {
    #pragma unroll
    for (int i = 0; i < 4; ++i) { gld16(pA[i], dA[i]); pA[i] += 64; }
    #pragma unroll
    for (int i = 0; i < 4; ++i) { gld16(pB[i], dB[i]); pB[i] += 64; }
    __syncthreads();
    v8h av0[2], av1[2], bv0[5], bv1[5];
    #pragma unroll
    for (int mf = 0; mf < 2; ++mf) {
      av0[mf] = *(const v8h*)(a0 + mf * 1024);
      av1[mf] = *(const v8h*)(a1 + mf * 1024);
    }
    #pragma unroll
    for (int nf = 0; nf < 5; ++nf) {
      bv0[nf] = *(const v8h*)(b0 + nf * 1024);
      bv1[nf] = *(const v8h*)(b1 + nf * 1024);
    }
    #pragma unroll
    for (int mf = 0; mf < 2; ++mf)
      #pragma unroll
      for (int nf = 0; nf < 5; ++nf) {
        acc[mf][nf] = __builtin_amdgcn_mfma_f32_16x16x32_f16(av0[mf], bv0[nf], acc[mf][nf], 0, 0, 0);
        acc[mf][nf] = __builtin_amdgcn_mfma_f32_16x16x32_f16(av1[mf], bv1[nf], acc[mf][nf], 0, 0, 0);
      }
    __syncthreads();
  }
  #pragma unroll
  for (int mf = 0; mf < 2; ++mf) {
    int rbase = m0 + w * 32 + mf * 16 + (lane >> 4) * 4;
    #pragma unroll
    for (int nf = 0; nf < 5; ++nf) {
      int col = nf * 16 + lrow;
      if (col < DI) {
        #pragma unroll
        for (int q = 0; q < 4; ++q) {
          int m = rbase + q;
          int t = m >> 11, b = m & (BB - 1);
          size_t oi = (size_t)b * TT * DI + t * DI + col;
          out[oi] = acc[mf][nf][q] + fb[col] + dec_in[oi];
        }
      }
    }
  }
}

// ---------------- launch ----------------
extern "C" void kernel_launch(void* const* d_in, const int* in_sizes, int n_in,
                              void* d_out, int out_size, void* d_ws, size_t ws_size,
                              hipStream_t stream)
{
  const float* enc_in = (const float*)d_in[0];
  const float* dec_in = (const float*)d_in[1];
  const float* noise  = (const float*)d_in[2];
  const float* Wih_e  = (const float*)d_in[3];
  const float* Whh_e  = (const float*)d_in[4];
  const float* bih_e  = (const float*)d_in[5];
  const float* bhh_e  = (const float*)d_in[6];
  const float* Wih_d  = (const float*)d_in[7];
  const float* Whh_d  = (const float*)d_in[8];
  const float* bih_d  = (const float*)d_in[9];
  const float* bhh_d  = (const float*)d_in[10];
  const float* fc1_w  = (const float*)d_in[11];
  const float* fc1_b  = (const float*)d_in[12];
  const float* mu_w   = (const float*)d_in[13];
  const float* mu_b   = (const float*)d_in[14];
  const float* sig_w  = (const float*)d_in[15];
  const float* sig_b  = (const float*)d_in[16];
  const float* t2v_w  = (const float*)d_in[17];
  const float* t2v_b  = (const float*)d_in[18];
  float* outp = (float*)d_out;

  char* ws = (char*)d_ws;
  size_t off = 0;
  auto alloc = [&](size_t bytes) -> char* {
    char* p = ws + off; off += (bytes + 255) & ~(size_t)255; return p;
  };
  f16*   wq_e   = (f16*)alloc((size_t)4096 * 1280 * 2);
  f16*   wq_d   = (f16*)alloc((size_t)4096 * 1152 * 2);
  f16*   fc1h   = (f16*)alloc((size_t)128 * RR * 2);
  float* bias_e = (float*)alloc(4096 * 4);
  float* bias_d = (float*)alloc(4096 * 4);
  f16*   feat_e = (f16*)alloc((size_t)SE * BB * 256 * 2);
  f16*   feat_d = (f16*)alloc((size_t)TT * BB * 128 * 2);
  f16*   h_ping = (f16*)alloc((size_t)BB * RR * 2);
  f16*   h_pong = (f16*)alloc((size_t)BB * RR * 2);
  float* cbuf   = (float*)alloc((size_t)BB * RR * 4);
  float* hf32   = (float*)alloc((size_t)BB * RR * 4);
  f16*   Hd     = (f16*)alloc((size_t)TT * BB * RR * 2);
  if (off > ws_size) return;   // workspace too small -> clean failure

  // prep
  prep_misc_kernel<<<(BB * RR + 255) / 256, 256, 0, stream>>>(
      cbuf, h_ping, bih_e, bhh_e, bih_d, bhh_d, bias_e, bias_d, fc1_w, fc1h);
  prep_wq_kernel<<<4096, 256, 0, stream>>>(Whh_e, Wih_e, wq_e, 1280, DI + EE);
  prep_wq_kernel<<<4096, 256, 0, stream>>>(Whh_d, Wih_d, wq_d, 1152, DI);
  feat_enc_kernel<<<SE * (BB / 32), 256, 0, stream>>>(enc_in, t2v_w, t2v_b, feat_e);
  feat_dec_kernel<<<(TT * BB * 128 + 255) / 256, 256, 0, stream>>>(dec_in, feat_d);

  dim3 sgrid(32, 16, 1);   // 1024/32 units x 2048/128 rows

  // encoder: 49 steps, h ping-pong, c in-place
  f16* hcur = h_ping; f16* hnxt = h_pong;
  for (int t = 0; t < SE; ++t) {
    const f16* ft = feat_e + (size_t)t * BB * 256;
    if (t == SE - 1)
      lstm_step_kernel<4, 256, true><<<sgrid, 256, 0, stream>>>(
          hcur, ft, wq_e, bias_e, cbuf, hnxt, hf32);
    else
      lstm_step_kernel<4, 256, false><<<sgrid, 256, 0, stream>>>(
          hcur, ft, wq_e, bias_e, cbuf, hnxt, nullptr);
    f16* tmp = hcur; hcur = hnxt; hnxt = tmp;
  }

  // normalize + noise (reads fp32 h, writes swizzled f16 h into h_ping, c in-place)
  musigma_kernel<<<BB, 256, 0, stream>>>(hf32, cbuf, noise, mu_w, mu_b, sig_w, sig_b, h_ping);

  // decoder: 25 steps, h chained through Hd slices
  const f16* din = h_ping;
  for (int t = 0; t < TT; ++t) {
    f16* hout = Hd + (size_t)t * BB * RR;
    lstm_step_kernel<2, 128, false><<<sgrid, 256, 0, stream>>>(
        din, feat_d + (size_t)t * BB * 128, wq_d, bias_d, cbuf, hout, nullptr);
    din = hout;
  }

  // out = dec_in + Hdec @ fc1^T + fc1_b
  final_fc_kernel<<<(TT * BB) / 128, 256, 0, stream>>>(Hd, fc1h, fc1_b, dec_in, outp);
}